// Round 6
// baseline (437.743 us; speedup 1.0000x reference)
//
#include <hip/hip_runtime.h>
#include <math.h>

#define NN 100000
#define NE 1200000
#define CC 64
#define GG 256
#define RR 8
#define EPSF 1e-5f
#define NBLK 98  // ceil(NN/1024)

// ---------- CSR build ----------
__global__ __launch_bounds__(256) void k_deg(const int* __restrict__ ei,
                                             int* __restrict__ degcnt) {
  int e = blockIdx.x * 256 + threadIdx.x;
  if (e < NE) atomicAdd(&degcnt[ei[NE + e]], 1);
}

__global__ __launch_bounds__(256) void k_scan1(const int* __restrict__ deg,
                                               int* __restrict__ rowptr,
                                               int* __restrict__ bsum) {
  __shared__ int sh[256];
  int t = threadIdx.x, blk = blockIdx.x;
  int base = blk * 1024 + t * 4;
  int v0 = base + 0 < NN ? deg[base + 0] : 0;
  int v1 = base + 1 < NN ? deg[base + 1] : 0;
  int v2 = base + 2 < NN ? deg[base + 2] : 0;
  int v3 = base + 3 < NN ? deg[base + 3] : 0;
  int s = v0 + v1 + v2 + v3;
  sh[t] = s;
  __syncthreads();
  for (int d = 1; d < 256; d <<= 1) {
    int val = sh[t];
    int add = (t >= d) ? sh[t - d] : 0;
    __syncthreads();
    sh[t] = val + add;
    __syncthreads();
  }
  int excl = sh[t] - s;
  if (base + 0 < NN) rowptr[base + 0] = excl;
  if (base + 1 < NN) rowptr[base + 1] = excl + v0;
  if (base + 2 < NN) rowptr[base + 2] = excl + v0 + v1;
  if (base + 3 < NN) rowptr[base + 3] = excl + v0 + v1 + v2;
  if (t == 255) bsum[blk] = sh[255];
}

__global__ __launch_bounds__(128) void k_scan2(int* __restrict__ bsum) {
  __shared__ int sh[128];
  int t = threadIdx.x;
  int v = t < NBLK ? bsum[t] : 0;
  sh[t] = v;
  __syncthreads();
  for (int d = 1; d < 128; d <<= 1) {
    int val = sh[t];
    int add = (t >= d) ? sh[t - d] : 0;
    __syncthreads();
    sh[t] = val + add;
    __syncthreads();
  }
  if (t < NBLK) bsum[t] = sh[t] - v;  // exclusive, in place
}

__global__ __launch_bounds__(256) void k_scan3(int* __restrict__ rowptr,
                                               const int* __restrict__ bsum,
                                               int* __restrict__ cursor) {
  int t = threadIdx.x, blk = blockIdx.x;
  int base = blk * 1024 + t * 4;
  int off = bsum[blk];
#pragma unroll
  for (int q = 0; q < 4; ++q) {
    int i = base + q;
    if (i < NN) {
      int r = rowptr[i] + off;
      rowptr[i] = r;
      cursor[i] = r;
    }
  }
  if (blk == 0 && t == 0) rowptr[NN] = NE;
}

__global__ __launch_bounds__(256) void k_fill(const int* __restrict__ ei,
                                              int* __restrict__ cursor,
                                              int* __restrict__ csr) {
  int e = blockIdx.x * 256 + threadIdx.x;
  if (e < NE) {
    int src = ei[e], dst = ei[NE + e];
    int pos = atomicAdd(&cursor[dst], 1);
    csr[pos] = src;
  }
}

// ---------- gather: agg[i] = sum of x[src] over in-edges ----------
__global__ __launch_bounds__(256) void k_gather(const float* __restrict__ x,
                                                const int* __restrict__ csr,
                                                const int* __restrict__ rowptr,
                                                float* __restrict__ h) {
  int w = blockIdx.x * 4 + (threadIdx.x >> 6);
  int lane = threadIdx.x & 63;
  if (w >= NN) return;
  int s = rowptr[w], e = rowptr[w + 1];
  float acc = 0.0f;
  int j = s;
  for (; j + 3 < e; j += 4) {
    int s0 = csr[j], s1 = csr[j + 1], s2 = csr[j + 2], s3 = csr[j + 3];
    acc += x[(size_t)s0 * CC + lane];
    acc += x[(size_t)s1 * CC + lane];
    acc += x[(size_t)s2 * CC + lane];
    acc += x[(size_t)s3 * CC + lane];
  }
  for (; j < e; ++j) acc += x[(size_t)csr[j] * CC + lane];
  h[(size_t)w * CC + lane] = acc;
}

// ---------- passA: h = (agg/deg)@Wl^T + bl + x@Wr^T, in place over h ----------
// Weights staged in LDS interleaved [c][k][{wl,wr}]; all 64 lanes read the
// same LDS address -> broadcast, conflict-free. 2 nodes/thread so each
// weight b128 read feeds 16 FMAs (halves LDS-pipe cost per node).
__global__ __launch_bounds__(128) void k_passA(
    const float* __restrict__ x, float* h, const int* __restrict__ rowptr,
    const float* __restrict__ Wl, const float* __restrict__ bl,
    const float* __restrict__ Wr) {
  __shared__ float Ws[CC * CC * 2];  // Ws[c*128 + 2k] = Wl[c][k], +1 = Wr[c][k]
  __shared__ float bls[CC];
  for (int idx = threadIdx.x; idx < CC * CC; idx += 128) {
    int c = idx >> 6, k = idx & 63;
    Ws[c * 128 + 2 * k]     = Wl[idx];
    Ws[c * 128 + 2 * k + 1] = Wr[idx];
  }
  if (threadIdx.x < CC) bls[threadIdx.x] = bl[threadIdx.x];
  __syncthreads();

  int iA = blockIdx.x * 256 + threadIdx.x;
  int iB = iA + 128;
  bool vA = iA < NN;
  bool vB = iB < NN;
  if (!vA && !vB) return;
  float invA = 1.0f, invB = 1.0f;
  if (vA) invA = 1.0f / fmaxf((float)(rowptr[iA + 1] - rowptr[iA]), 1.0f);
  if (vB) invB = 1.0f / fmaxf((float)(rowptr[iB + 1] - rowptr[iB]), 1.0f);
  const float4* apA = (const float4*)(h + (size_t)iA * CC);
  const float4* xpA = (const float4*)(x + (size_t)iA * CC);
  const float4* apB = (const float4*)(h + (size_t)iB * CC);
  const float4* xpB = (const float4*)(x + (size_t)iB * CC);

  float accA[CC], accB[CC];
#pragma unroll
  for (int c = 0; c < CC; ++c) { float b = bls[c]; accA[c] = b; accB[c] = b; }

#pragma unroll 2
  for (int kb = 0; kb < 16; ++kb) {
    float4 aA = vA ? apA[kb] : make_float4(0.f, 0.f, 0.f, 0.f);
    float4 xA = vA ? xpA[kb] : make_float4(0.f, 0.f, 0.f, 0.f);
    float4 aB = vB ? apB[kb] : make_float4(0.f, 0.f, 0.f, 0.f);
    float4 xB = vB ? xpB[kb] : make_float4(0.f, 0.f, 0.f, 0.f);
    float a0A = aA.x * invA, a1A = aA.y * invA, a2A = aA.z * invA, a3A = aA.w * invA;
    float a0B = aB.x * invB, a1B = aB.y * invB, a2B = aB.z * invB, a3B = aB.w * invB;
    const float4* wrow = (const float4*)(Ws + kb * 8);
#pragma unroll
    for (int c = 0; c < CC; ++c) {
      float4 w0 = wrow[c * 32 + 0];  // wl[k0], wr[k0], wl[k1], wr[k1]
      float4 w1 = wrow[c * 32 + 1];  // wl[k2], wr[k2], wl[k3], wr[k3]
      float tA = accA[c], tB = accB[c];
      tA = fmaf(a0A, w0.x, tA); tB = fmaf(a0B, w0.x, tB);
      tA = fmaf(xA.x, w0.y, tA); tB = fmaf(xB.x, w0.y, tB);
      tA = fmaf(a1A, w0.z, tA); tB = fmaf(a1B, w0.z, tB);
      tA = fmaf(xA.y, w0.w, tA); tB = fmaf(xB.y, w0.w, tB);
      tA = fmaf(a2A, w1.x, tA); tB = fmaf(a2B, w1.x, tB);
      tA = fmaf(xA.z, w1.y, tA); tB = fmaf(xB.z, w1.y, tB);
      tA = fmaf(a3A, w1.z, tA); tB = fmaf(a3B, w1.z, tB);
      tA = fmaf(xA.w, w1.w, tA); tB = fmaf(xB.w, w1.w, tB);
      accA[c] = tA; accB[c] = tB;
    }
  }
  if (vA) {
    float4* hp = (float4*)(h + (size_t)iA * CC);
#pragma unroll
    for (int q = 0; q < 16; ++q)
      hp[q] = make_float4(accA[4 * q], accA[4 * q + 1], accA[4 * q + 2], accA[4 * q + 3]);
  }
  if (vB) {
    float4* hp = (float4*)(h + (size_t)iB * CC);
#pragma unroll
    for (int q = 0; q < 16; ++q)
      hp[q] = make_float4(accB[4 * q], accB[4 * q + 1], accB[4 * q + 2], accB[4 * q + 3]);
  }
}

// ---------- stats: segmented per-graph sum(h), sum(h^2), count (batch sorted) ----------
__global__ __launch_bounds__(256) void k_stats(const float* __restrict__ h,
                                               const int* __restrict__ batch,
                                               float* __restrict__ sumH,
                                               float* __restrict__ sumH2,
                                               float* __restrict__ cntg) {
  int w = blockIdx.x * 4 + (threadIdx.x >> 6);
  int lane = threadIdx.x & 63;
  int i0 = w * 64;
  if (i0 >= NN) return;
  int iend = i0 + 64 < NN ? i0 + 64 : NN;
  int gcur = batch[i0];
  float aH = 0.0f, aH2 = 0.0f;
  int run = 0;
  for (int i = i0; i < iend; ++i) {
    int g = batch[i];  // wave-uniform
    if (g != gcur) {
      atomicAdd(&sumH[(size_t)gcur * CC + lane], aH);
      atomicAdd(&sumH2[(size_t)gcur * CC + lane], aH2);
      if (lane == 0) atomicAdd(&cntg[gcur], (float)run);
      aH = 0.0f; aH2 = 0.0f; run = 0;
      gcur = g;
    }
    float v = h[(size_t)i * CC + lane];
    aH += v;
    aH2 += v * v;
    run++;
  }
  atomicAdd(&sumH[(size_t)gcur * CC + lane], aH);
  atomicAdd(&sumH2[(size_t)gcur * CC + lane], aH2);
  if (lane == 0) atomicAdd(&cntg[gcur], (float)run);
}

// ---------- passC: normalize (closed-form var) + gate + residual + relu ----------
// All small params staged in LDS (avoids HBM re-fetch under stream eviction).
__global__ __launch_bounds__(256) void k_passC(
    const float* __restrict__ h, const float* __restrict__ x,
    const int* __restrict__ batch, const float* __restrict__ sumH,
    const float* __restrict__ sumH2, const float* __restrict__ cntg,
    const float* __restrict__ gw, const float* __restrict__ gb,
    const float* __restrict__ alpha, const float* __restrict__ a1w,
    const float* __restrict__ a1b, const float* __restrict__ a2w,
    const float* __restrict__ a2b, float* __restrict__ out) {
  __shared__ float A1[RR * CC];   // a1w
  __shared__ float A2[CC * RR];   // a2w
  __shared__ float A1B[RR];
  __shared__ float PRM[4 * CC];   // a2b | gw | gb | alpha
  for (int idx = threadIdx.x; idx < RR * CC; idx += 256) {
    A1[idx] = a1w[idx];
    A2[idx] = a2w[idx];
  }
  if (threadIdx.x < RR) A1B[threadIdx.x] = a1b[threadIdx.x];
  if (threadIdx.x < CC) {
    PRM[threadIdx.x] = a2b[threadIdx.x];
    PRM[CC + threadIdx.x] = gw[threadIdx.x];
    PRM[2 * CC + threadIdx.x] = gb[threadIdx.x];
    PRM[3 * CC + threadIdx.x] = alpha[threadIdx.x];
  }
  __syncthreads();

  int i = blockIdx.x * 256 + threadIdx.x;
  if (i >= NN) return;
  int g = batch[i];
  float rn = 1.0f / fmaxf(cntg[g], 1.0f);
  float xv[CC];
  const float4* xp = (const float4*)(x + (size_t)i * CC);
#pragma unroll
  for (int q = 0; q < 16; ++q) {
    float4 b = xp[q];
    xv[4 * q] = b.x; xv[4 * q + 1] = b.y; xv[4 * q + 2] = b.z; xv[4 * q + 3] = b.w;
  }
  // channel-attention hidden layer (LDS broadcast reads)
  float p[RR];
#pragma unroll
  for (int r = 0; r < RR; ++r) {
    float acc = A1B[r];
#pragma unroll
    for (int k = 0; k < CC; ++k) acc = fmaf(xv[k], A1[r * CC + k], acc);
    p[r] = fmaxf(acc, 0.0f);
  }
  const float4* hp = (const float4*)(h + (size_t)i * CC);
  const float4* sHp = (const float4*)(sumH + (size_t)g * CC);
  const float4* sH2p = (const float4*)(sumH2 + (size_t)g * CC);
  float4* op = (float4*)(out + (size_t)i * CC);
#pragma unroll 4
  for (int q = 0; q < 16; ++q) {
    float4 h4 = hp[q];
    float4 sH = sHp[q];
    float4 sH2 = sH2p[q];
    float hv[4] = {h4.x, h4.y, h4.z, h4.w};
    float sh[4] = {sH.x, sH.y, sH.z, sH.w};
    float sh2[4] = {sH2.x, sH2.y, sH2.z, sH2.w};
    float res[4];
#pragma unroll
    for (int u = 0; u < 4; ++u) {
      int c = q * 4 + u;
      float mu = sh[u] * rn;
      float t = PRM[3 * CC + c] * mu;                     // alpha*mu
      float var = sh2[u] * rn - 2.0f * mu * t + t * t;
      float o = hv[u] - t;
      float y = fmaf(PRM[CC + c] * o, rsqrtf(var + EPSF), PRM[2 * CC + c]);
      float gacc = PRM[c];                                // a2b
#pragma unroll
      for (int r = 0; r < RR; ++r) gacc = fmaf(p[r], A2[c * RR + r], gacc);
      float gate = 1.0f / (1.0f + __expf(-gacc));
      res[u] = fmaxf(y + gate * xv[c], 0.0f);
    }
    op[q] = make_float4(res[0], res[1], res[2], res[3]);
  }
}

extern "C" void kernel_launch(void* const* d_in, const int* in_sizes, int n_in,
                              void* d_out, int out_size, void* d_ws, size_t ws_size,
                              hipStream_t stream) {
  const float* x        = (const float*)d_in[0];
  const int*   ei       = (const int*)d_in[1];
  const int*   batch    = (const int*)d_in[2];
  const float* Wl       = (const float*)d_in[3];
  const float* bl       = (const float*)d_in[4];
  const float* Wr       = (const float*)d_in[5];
  const float* gn_w     = (const float*)d_in[6];
  const float* gn_b     = (const float*)d_in[7];
  const float* gn_alpha = (const float*)d_in[8];
  const float* a1w      = (const float*)d_in[9];
  const float* a1b      = (const float*)d_in[10];
  const float* a2w      = (const float*)d_in[11];
  const float* a2b      = (const float*)d_in[12];
  float* out = (float*)d_out;

  // workspace layout (floats/ints, 4B units)
  float* h      = (float*)d_ws;                    // NN*CC (agg -> h in place)
  int*   degcnt = (int*)(h + (size_t)NN * CC);     // NN (reused as cursor)
  float* sumH   = (float*)(degcnt + NN);           // GG*CC
  float* sumH2  = sumH + GG * CC;                  // GG*CC
  float* cntg   = sumH2 + GG * CC;                 // GG
  int*   bsum   = (int*)(cntg + GG);               // 128
  int*   rowptr = bsum + 128;                      // NN+1
  int*   csr    = rowptr + NN + 1;                 // NE

  // zero: degcnt + sumH + sumH2 + cntg + bsum
  size_t zbytes = ((size_t)NN + 2 * GG * CC + GG + 128) * sizeof(int);
  hipMemsetAsync((void*)degcnt, 0, zbytes, stream);

  k_deg  <<<(NE + 255) / 256, 256, 0, stream>>>(ei, degcnt);
  k_scan1<<<NBLK, 256, 0, stream>>>(degcnt, rowptr, bsum);
  k_scan2<<<1, 128, 0, stream>>>(bsum);
  k_scan3<<<NBLK, 256, 0, stream>>>(rowptr, bsum, degcnt /*cursor*/);
  k_fill <<<(NE + 255) / 256, 256, 0, stream>>>(ei, degcnt /*cursor*/, csr);
  k_gather<<<(NN + 3) / 4, 256, 0, stream>>>(x, csr, rowptr, h);
  k_passA<<<(NN + 511) / 512 * 2, 128, 0, stream>>>(x, h, rowptr, Wl, bl, Wr);
  k_stats<<<((NN + 63) / 64 + 3) / 4, 256, 0, stream>>>(h, batch, sumH, sumH2, cntg);
  k_passC<<<(NN + 255) / 256, 256, 0, stream>>>(h, x, batch, sumH, sumH2, cntg,
                                                gn_w, gn_b, gn_alpha,
                                                a1w, a1b, a2w, a2b, out);
}

// Round 7
// 317.671 us; speedup vs baseline: 1.3780x; 1.3780x over previous
//
#include <hip/hip_runtime.h>
#include <math.h>

#define NN 100000
#define NE 1200000
#define CC 64
#define GG 256
#define RR 8
#define EPSF 1e-5f
#define NBLK 98  // ceil(NN/1024)
#define WQ 2052  // per-quarter LDS stride in floats (16c*128 + 4 pad -> bank shift 4, 16B aligned)

// ---------- CSR build ----------
__global__ __launch_bounds__(256) void k_deg(const int* __restrict__ ei,
                                             int* __restrict__ degcnt) {
  int e = blockIdx.x * 256 + threadIdx.x;
  if (e < NE) atomicAdd(&degcnt[ei[NE + e]], 1);
}

__global__ __launch_bounds__(256) void k_scan1(const int* __restrict__ deg,
                                               int* __restrict__ rowptr,
                                               int* __restrict__ bsum) {
  __shared__ int sh[256];
  int t = threadIdx.x, blk = blockIdx.x;
  int base = blk * 1024 + t * 4;
  int v0 = base + 0 < NN ? deg[base + 0] : 0;
  int v1 = base + 1 < NN ? deg[base + 1] : 0;
  int v2 = base + 2 < NN ? deg[base + 2] : 0;
  int v3 = base + 3 < NN ? deg[base + 3] : 0;
  int s = v0 + v1 + v2 + v3;
  sh[t] = s;
  __syncthreads();
  for (int d = 1; d < 256; d <<= 1) {
    int val = sh[t];
    int add = (t >= d) ? sh[t - d] : 0;
    __syncthreads();
    sh[t] = val + add;
    __syncthreads();
  }
  int excl = sh[t] - s;
  if (base + 0 < NN) rowptr[base + 0] = excl;
  if (base + 1 < NN) rowptr[base + 1] = excl + v0;
  if (base + 2 < NN) rowptr[base + 2] = excl + v0 + v1;
  if (base + 3 < NN) rowptr[base + 3] = excl + v0 + v1 + v2;
  if (t == 255) bsum[blk] = sh[255];
}

__global__ __launch_bounds__(128) void k_scan2(int* __restrict__ bsum) {
  __shared__ int sh[128];
  int t = threadIdx.x;
  int v = t < NBLK ? bsum[t] : 0;
  sh[t] = v;
  __syncthreads();
  for (int d = 1; d < 128; d <<= 1) {
    int val = sh[t];
    int add = (t >= d) ? sh[t - d] : 0;
    __syncthreads();
    sh[t] = val + add;
    __syncthreads();
  }
  if (t < NBLK) bsum[t] = sh[t] - v;  // exclusive, in place
}

__global__ __launch_bounds__(256) void k_scan3(int* __restrict__ rowptr,
                                               const int* __restrict__ bsum,
                                               int* __restrict__ cursor) {
  int t = threadIdx.x, blk = blockIdx.x;
  int base = blk * 1024 + t * 4;
  int off = bsum[blk];
#pragma unroll
  for (int q = 0; q < 4; ++q) {
    int i = base + q;
    if (i < NN) {
      int r = rowptr[i] + off;
      rowptr[i] = r;
      cursor[i] = r;
    }
  }
  if (blk == 0 && t == 0) rowptr[NN] = NE;
}

__global__ __launch_bounds__(256) void k_fill(const int* __restrict__ ei,
                                              int* __restrict__ cursor,
                                              int* __restrict__ csr) {
  int e = blockIdx.x * 256 + threadIdx.x;
  if (e < NE) {
    int src = ei[e], dst = ei[NE + e];
    int pos = atomicAdd(&cursor[dst], 1);
    csr[pos] = src;
  }
}

// ---------- gather: agg[i] = sum of x[src] over in-edges ----------
__global__ __launch_bounds__(256) void k_gather(const float* __restrict__ x,
                                                const int* __restrict__ csr,
                                                const int* __restrict__ rowptr,
                                                float* __restrict__ h) {
  int w = blockIdx.x * 4 + (threadIdx.x >> 6);
  int lane = threadIdx.x & 63;
  if (w >= NN) return;
  int s = rowptr[w], e = rowptr[w + 1];
  float acc = 0.0f;
  int j = s;
  for (; j + 3 < e; j += 4) {
    int s0 = csr[j], s1 = csr[j + 1], s2 = csr[j + 2], s3 = csr[j + 3];
    acc += x[(size_t)s0 * CC + lane];
    acc += x[(size_t)s1 * CC + lane];
    acc += x[(size_t)s2 * CC + lane];
    acc += x[(size_t)s3 * CC + lane];
  }
  for (; j < e; ++j) acc += x[(size_t)csr[j] * CC + lane];
  h[(size_t)w * CC + lane] = acc;
}

// ---------- passA: h = (agg/deg)@Wl^T + bl + x@Wr^T, in place over h ----------
// Wave-tile = 32 nodes. Lane l: nodes n=l&15 and n+16; output quarter q=l>>4.
// acc = 2x16 regs (no spill). Weights in LDS, {wl,wr}-interleaved, quarter
// stride 2052 floats -> the 4 per-wave addresses hit 4 distinct banks
// (conflict-free broadcast). In-place safe: a wave reads only its own 32
// rows, and all reads precede all stores in its instruction stream.
__global__ __launch_bounds__(256) void k_passA(
    const float* __restrict__ x, float* h, const int* __restrict__ rowptr,
    const float* __restrict__ Wl, const float* __restrict__ bl,
    const float* __restrict__ Wr) {
  __shared__ float Ws[4 * WQ];  // [q][j][k][{l,r}] + pad
  __shared__ float bls[CC];
  for (int idx = threadIdx.x; idx < CC * CC; idx += 256) {
    int q = idx >> 10, j = (idx >> 6) & 15, k = idx & 63;
    Ws[q * WQ + j * 128 + 2 * k]     = Wl[idx];
    Ws[q * WQ + j * 128 + 2 * k + 1] = Wr[idx];
  }
  if (threadIdx.x < CC) bls[threadIdx.x] = bl[threadIdx.x];
  __syncthreads();

  int lane = threadIdx.x & 63;
  int wave = threadIdx.x >> 6;
  int n = lane & 15;
  int q = lane >> 4;
  int iA = blockIdx.x * 128 + wave * 32 + n;
  int iB = iA + 16;
  int cA = iA < NN ? iA : NN - 1;
  int cB = iB < NN ? iB : NN - 1;
  float invA = 1.0f / fmaxf((float)(rowptr[cA + 1] - rowptr[cA]), 1.0f);
  float invB = 1.0f / fmaxf((float)(rowptr[cB + 1] - rowptr[cB]), 1.0f);
  const float4* apA = (const float4*)(h + (size_t)cA * CC);
  const float4* xpA = (const float4*)(x + (size_t)cA * CC);
  const float4* apB = (const float4*)(h + (size_t)cB * CC);
  const float4* xpB = (const float4*)(x + (size_t)cB * CC);
  const float4* wq = (const float4*)Ws + q * (WQ / 4);  // + j*32 + kb*2

  float accA[16], accB[16];
#pragma unroll
  for (int j = 0; j < 16; ++j) {
    float b = bls[q * 16 + j];
    accA[j] = b; accB[j] = b;
  }

#pragma unroll 2
  for (int kb = 0; kb < 16; ++kb) {
    float4 aA = apA[kb], xA = xpA[kb];
    float4 aB = apB[kb], xB = xpB[kb];
    float a0A = aA.x * invA, a1A = aA.y * invA, a2A = aA.z * invA, a3A = aA.w * invA;
    float a0B = aB.x * invB, a1B = aB.y * invB, a2B = aB.z * invB, a3B = aB.w * invB;
#pragma unroll
    for (int j = 0; j < 16; ++j) {
      float4 w0 = wq[j * 32 + kb * 2];      // {wl[k0],wr[k0],wl[k1],wr[k1]}
      float4 w1 = wq[j * 32 + kb * 2 + 1];  // {wl[k2],wr[k2],wl[k3],wr[k3]}
      float tA = accA[j], tB = accB[j];
      tA = fmaf(a0A, w0.x, tA); tB = fmaf(a0B, w0.x, tB);
      tA = fmaf(xA.x, w0.y, tA); tB = fmaf(xB.x, w0.y, tB);
      tA = fmaf(a1A, w0.z, tA); tB = fmaf(a1B, w0.z, tB);
      tA = fmaf(xA.y, w0.w, tA); tB = fmaf(xB.y, w0.w, tB);
      tA = fmaf(a2A, w1.x, tA); tB = fmaf(a2B, w1.x, tB);
      tA = fmaf(xA.z, w1.y, tA); tB = fmaf(xB.z, w1.y, tB);
      tA = fmaf(a3A, w1.z, tA); tB = fmaf(a3B, w1.z, tB);
      tA = fmaf(xA.w, w1.w, tA); tB = fmaf(xB.w, w1.w, tB);
      accA[j] = tA; accB[j] = tB;
    }
  }
  if (iA < NN) {
    float4* hp = (float4*)(h + (size_t)iA * CC + q * 16);
#pragma unroll
    for (int r = 0; r < 4; ++r)
      hp[r] = make_float4(accA[4 * r], accA[4 * r + 1], accA[4 * r + 2], accA[4 * r + 3]);
  }
  if (iB < NN) {
    float4* hp = (float4*)(h + (size_t)iB * CC + q * 16);
#pragma unroll
    for (int r = 0; r < 4; ++r)
      hp[r] = make_float4(accB[4 * r], accB[4 * r + 1], accB[4 * r + 2], accB[4 * r + 3]);
  }
}

// ---------- stats: segmented per-graph sum(h), sum(h^2), count (batch sorted) ----------
__global__ __launch_bounds__(256) void k_stats(const float* __restrict__ h,
                                               const int* __restrict__ batch,
                                               float* __restrict__ sumH,
                                               float* __restrict__ sumH2,
                                               float* __restrict__ cntg) {
  int w = blockIdx.x * 4 + (threadIdx.x >> 6);
  int lane = threadIdx.x & 63;
  int i0 = w * 64;
  if (i0 >= NN) return;
  int iend = i0 + 64 < NN ? i0 + 64 : NN;
  int gcur = batch[i0];
  float aH = 0.0f, aH2 = 0.0f;
  int run = 0;
  for (int i = i0; i < iend; ++i) {
    int g = batch[i];  // wave-uniform
    if (g != gcur) {
      atomicAdd(&sumH[(size_t)gcur * CC + lane], aH);
      atomicAdd(&sumH2[(size_t)gcur * CC + lane], aH2);
      if (lane == 0) atomicAdd(&cntg[gcur], (float)run);
      aH = 0.0f; aH2 = 0.0f; run = 0;
      gcur = g;
    }
    float v = h[(size_t)i * CC + lane];
    aH += v;
    aH2 += v * v;
    run++;
  }
  atomicAdd(&sumH[(size_t)gcur * CC + lane], aH);
  atomicAdd(&sumH2[(size_t)gcur * CC + lane], aH2);
  if (lane == 0) atomicAdd(&cntg[gcur], (float)run);
}

// ---------- passC: normalize (closed-form var) + gate + residual + relu ----------
__global__ __launch_bounds__(256) void k_passC(
    const float* __restrict__ h, const float* __restrict__ x,
    const int* __restrict__ batch, const float* __restrict__ sumH,
    const float* __restrict__ sumH2, const float* __restrict__ cntg,
    const float* __restrict__ gw, const float* __restrict__ gb,
    const float* __restrict__ alpha, const float* __restrict__ a1w,
    const float* __restrict__ a1b, const float* __restrict__ a2w,
    const float* __restrict__ a2b, float* __restrict__ out) {
  __shared__ float A1[RR * CC];   // a1w
  __shared__ float A2[CC * RR];   // a2w
  __shared__ float A1B[RR];
  __shared__ float PRM[4 * CC];   // a2b | gw | gb | alpha
  for (int idx = threadIdx.x; idx < RR * CC; idx += 256) {
    A1[idx] = a1w[idx];
    A2[idx] = a2w[idx];
  }
  if (threadIdx.x < RR) A1B[threadIdx.x] = a1b[threadIdx.x];
  if (threadIdx.x < CC) {
    PRM[threadIdx.x] = a2b[threadIdx.x];
    PRM[CC + threadIdx.x] = gw[threadIdx.x];
    PRM[2 * CC + threadIdx.x] = gb[threadIdx.x];
    PRM[3 * CC + threadIdx.x] = alpha[threadIdx.x];
  }
  __syncthreads();

  int i = blockIdx.x * 256 + threadIdx.x;
  if (i >= NN) return;
  int g = batch[i];
  float rn = 1.0f / fmaxf(cntg[g], 1.0f);
  float xv[CC];
  const float4* xp = (const float4*)(x + (size_t)i * CC);
#pragma unroll
  for (int q = 0; q < 16; ++q) {
    float4 b = xp[q];
    xv[4 * q] = b.x; xv[4 * q + 1] = b.y; xv[4 * q + 2] = b.z; xv[4 * q + 3] = b.w;
  }
  // channel-attention hidden layer (LDS broadcast reads)
  float p[RR];
#pragma unroll
  for (int r = 0; r < RR; ++r) {
    float acc = A1B[r];
#pragma unroll
    for (int k = 0; k < CC; ++k) acc = fmaf(xv[k], A1[r * CC + k], acc);
    p[r] = fmaxf(acc, 0.0f);
  }
  const float4* hp = (const float4*)(h + (size_t)i * CC);
  const float4* sHp = (const float4*)(sumH + (size_t)g * CC);
  const float4* sH2p = (const float4*)(sumH2 + (size_t)g * CC);
  float4* op = (float4*)(out + (size_t)i * CC);
#pragma unroll 4
  for (int q = 0; q < 16; ++q) {
    float4 h4 = hp[q];
    float4 sH = sHp[q];
    float4 sH2 = sH2p[q];
    float hv[4] = {h4.x, h4.y, h4.z, h4.w};
    float sh[4] = {sH.x, sH.y, sH.z, sH.w};
    float sh2[4] = {sH2.x, sH2.y, sH2.z, sH2.w};
    float res[4];
#pragma unroll
    for (int u = 0; u < 4; ++u) {
      int c = q * 4 + u;
      float mu = sh[u] * rn;
      float t = PRM[3 * CC + c] * mu;                     // alpha*mu
      float var = sh2[u] * rn - 2.0f * mu * t + t * t;
      float o = hv[u] - t;
      float y = fmaf(PRM[CC + c] * o, rsqrtf(var + EPSF), PRM[2 * CC + c]);
      float gacc = PRM[c];                                // a2b
#pragma unroll
      for (int r = 0; r < RR; ++r) gacc = fmaf(p[r], A2[c * RR + r], gacc);
      float gate = 1.0f / (1.0f + __expf(-gacc));
      res[u] = fmaxf(y + gate * xv[c], 0.0f);
    }
    op[q] = make_float4(res[0], res[1], res[2], res[3]);
  }
}

extern "C" void kernel_launch(void* const* d_in, const int* in_sizes, int n_in,
                              void* d_out, int out_size, void* d_ws, size_t ws_size,
                              hipStream_t stream) {
  const float* x        = (const float*)d_in[0];
  const int*   ei       = (const int*)d_in[1];
  const int*   batch    = (const int*)d_in[2];
  const float* Wl       = (const float*)d_in[3];
  const float* bl       = (const float*)d_in[4];
  const float* Wr       = (const float*)d_in[5];
  const float* gn_w     = (const float*)d_in[6];
  const float* gn_b     = (const float*)d_in[7];
  const float* gn_alpha = (const float*)d_in[8];
  const float* a1w      = (const float*)d_in[9];
  const float* a1b      = (const float*)d_in[10];
  const float* a2w      = (const float*)d_in[11];
  const float* a2b      = (const float*)d_in[12];
  float* out = (float*)d_out;

  // workspace layout (floats/ints, 4B units)
  float* h      = (float*)d_ws;                    // NN*CC (agg -> h in place)
  int*   degcnt = (int*)(h + (size_t)NN * CC);     // NN (reused as cursor)
  float* sumH   = (float*)(degcnt + NN);           // GG*CC
  float* sumH2  = sumH + GG * CC;                  // GG*CC
  float* cntg   = sumH2 + GG * CC;                 // GG
  int*   bsum   = (int*)(cntg + GG);               // 128
  int*   rowptr = bsum + 128;                      // NN+1
  int*   csr    = rowptr + NN + 1;                 // NE

  // zero: degcnt + sumH + sumH2 + cntg + bsum
  size_t zbytes = ((size_t)NN + 2 * GG * CC + GG + 128) * sizeof(int);
  hipMemsetAsync((void*)degcnt, 0, zbytes, stream);

  k_deg  <<<(NE + 255) / 256, 256, 0, stream>>>(ei, degcnt);
  k_scan1<<<NBLK, 256, 0, stream>>>(degcnt, rowptr, bsum);
  k_scan2<<<1, 128, 0, stream>>>(bsum);
  k_scan3<<<NBLK, 256, 0, stream>>>(rowptr, bsum, degcnt /*cursor*/);
  k_fill <<<(NE + 255) / 256, 256, 0, stream>>>(ei, degcnt /*cursor*/, csr);
  k_gather<<<(NN + 3) / 4, 256, 0, stream>>>(x, csr, rowptr, h);
  k_passA<<<(NN + 127) / 128, 256, 0, stream>>>(x, h, rowptr, Wl, bl, Wr);
  k_stats<<<((NN + 63) / 64 + 3) / 4, 256, 0, stream>>>(h, batch, sumH, sumH2, cntg);
  k_passC<<<(NN + 255) / 256, 256, 0, stream>>>(h, x, batch, sumH, sumH2, cntg,
                                                gn_w, gn_b, gn_alpha,
                                                a1w, a1b, a2w, a2b, out);
}